// Round 1
// baseline (720.540 us; speedup 1.0000x reference)
//
#include <hip/hip_runtime.h>
#include <math.h>

#define N_PTS 4096
#define CH 64
#define INV_SQRT2 0.70710678118654752440f

// ---------------------------------------------------------------------------
// Kernel A/D: 64->64->64 MLP with leaky relu + per-group partial stats.
// Block = 256 threads = 4 waves; wave w handles row n0+w, lane = channel.
// ---------------------------------------------------------------------------
__global__ __launch_bounds__(256) void mlp_gn_kernel(
    const float* __restrict__ inp,
    const float* __restrict__ W1, const float* __restrict__ b1,
    const float* __restrict__ W2, const float* __restrict__ b2,
    float* __restrict__ pre_out, float* __restrict__ partials)
{
    __shared__ float in_s[4][64];
    __shared__ float h1_s[4][64];
    __shared__ float red_s[4][8];

    const int tid = threadIdx.x;
    const int lane = tid & 63;
    const int wid = tid >> 6;
    const int n0 = blockIdx.x * 4;

    in_s[wid][lane] = inp[n0 * 64 + tid];   // tid == wid*64+lane, coalesced
    __syncthreads();

    const int c = lane;
    float h = b1[c];
#pragma unroll
    for (int k4 = 0; k4 < 16; ++k4) {
        float4 wv = *(const float4*)&W1[c * 64 + k4 * 4];
        h = fmaf(in_s[wid][k4*4+0], wv.x, h);
        h = fmaf(in_s[wid][k4*4+1], wv.y, h);
        h = fmaf(in_s[wid][k4*4+2], wv.z, h);
        h = fmaf(in_s[wid][k4*4+3], wv.w, h);
    }
    h = (h >= 0.f) ? h : 0.2f * h;
    h1_s[wid][c] = h;
    __syncthreads();

    float g = b2[c];
#pragma unroll
    for (int k4 = 0; k4 < 16; ++k4) {
        float4 wv = *(const float4*)&W2[c * 64 + k4 * 4];
        g = fmaf(h1_s[wid][k4*4+0], wv.x, g);
        g = fmaf(h1_s[wid][k4*4+1], wv.y, g);
        g = fmaf(h1_s[wid][k4*4+2], wv.z, g);
        g = fmaf(h1_s[wid][k4*4+3], wv.w, g);
    }
    g = (g >= 0.f) ? g : 0.2f * g;
    pre_out[n0 * 64 + tid] = g;

    // partial stats per group (group = channel/16). 16-lane xor-reduce.
    float v = g, v2 = g * g;
#pragma unroll
    for (int m = 1; m < 16; m <<= 1) {
        v  += __shfl_xor(v,  m, 64);
        v2 += __shfl_xor(v2, m, 64);
    }
    if ((lane & 15) == 0) {
        int grp = lane >> 4;
        red_s[wid][grp * 2 + 0] = v;
        red_s[wid][grp * 2 + 1] = v2;
    }
    __syncthreads();
    if (tid < 8) {
        int grp = tid >> 1, which = tid & 1;
        float s = red_s[0][grp*2+which] + red_s[1][grp*2+which]
                + red_s[2][grp*2+which] + red_s[3][grp*2+which];
        partials[blockIdx.x * 8 + grp * 2 + which] = s;
    }
}

// ---------------------------------------------------------------------------
// Kernel B/E: finalize group stats -> per-channel scale/shift.
// ---------------------------------------------------------------------------
__global__ void finalize_kernel(
    const float* __restrict__ partials, int nblocks,
    const float* __restrict__ gw, const float* __restrict__ gb,
    float* __restrict__ ss)
{
    __shared__ float mean_s[4], inv_s[4];
    const int tid = threadIdx.x;
    if (tid < 4) {
        float S = 0.f, SS = 0.f;
        for (int b = 0; b < nblocks; ++b) {
            S  += partials[b * 8 + tid * 2 + 0];
            SS += partials[b * 8 + tid * 2 + 1];
        }
        const float cnt = (float)N_PTS * 16.f;
        float mean = S / cnt;
        float var = SS / cnt - mean * mean;
        mean_s[tid] = mean;
        inv_s[tid] = rsqrtf(var + 1e-5f);
    }
    __syncthreads();
    if (tid < 64) {
        int grp = tid >> 4;
        float sc = gw[tid] * inv_s[grp];
        ss[tid] = sc;
        ss[64 + tid] = gb[tid] - mean_s[grp] * sc;
    }
}

// ---------------------------------------------------------------------------
// Kernel C: the N^2 pairwise quasi-geodesic interaction.
// Block = 256 threads = 4 waves. Wave wid owns i = blockIdx*4+wid.
// Lane = output channel h. j-loop tiled by 64.
//  phase 1: lane j' computes per-pair {w*hcut[0..7], w} -> LDS
//  phase 2: per j: z = sum_c p[c]*A2[h,c] + p[8]*c2[h]; acc += relu(z)*f[j,h]
// (valid because w>0: w*relu(q) == relu(w*q))
// ---------------------------------------------------------------------------
__global__ __launch_bounds__(256) void pairwise_kernel(
    const float* __restrict__ points, const float* __restrict__ nuv,
    const float* __restrict__ f_pre, const float* __restrict__ ss_in,
    const float* __restrict__ A1, const float* __restrict__ c1,
    const float* __restrict__ A2, const float* __restrict__ c2,
    float* __restrict__ out_raw)
{
    __shared__ float f_s[64][64];
    __shared__ __align__(16) float pair_s[4][64][12];

    const int tid = threadIdx.x;
    const int lane = tid & 63;
    const int wid = tid >> 6;
    const int i = blockIdx.x * 4 + wid;

    // wave-uniform i data
    const float pix = points[i*3+0] * INV_SQRT2;
    const float piy = points[i*3+1] * INV_SQRT2;
    const float piz = points[i*3+2] * INV_SQRT2;
    float ni[9];
#pragma unroll
    for (int k = 0; k < 9; ++k) ni[k] = nuv[i*9+k];

    // conv MLP consts (uniform -> SGPRs)
    float a1v[8][3], c1v[8];
#pragma unroll
    for (int cc = 0; cc < 8; ++cc) {
        a1v[cc][0] = A1[cc*3+0]; a1v[cc][1] = A1[cc*3+1]; a1v[cc][2] = A1[cc*3+2];
        c1v[cc] = c1[cc];
    }
    // per-lane channel data
    float a2r[8];
#pragma unroll
    for (int cc = 0; cc < 8; ++cc) a2r[cc] = A2[lane*8+cc];
    const float c2r = c2[lane];
    const float myscale = ss_in[lane];
    const float myshift = ss_in[64 + lane];

    float acc = 0.f;

    for (int jc = 0; jc < 64; ++jc) {
        __syncthreads();   // protect f_s / pair_s from previous iteration readers
        // stage f tile (64 j x 64 ch), apply input-groupnorm affine on load
#pragma unroll
        for (int r = 0; r < 16; ++r) {
            int flat = r * 256 + tid;            // channel == tid&63 for all r
            f_s[flat >> 6][flat & 63] = f_pre[jc * 4096 + flat] * myscale + myshift;
        }
        // phase 1: per-pair scalars for j = jc*64 + lane
        {
            const int j = jc * 64 + lane;
            float px = points[j*3+0] * INV_SQRT2 - pix;
            float py = points[j*3+1] * INV_SQRT2 - piy;
            float pz = points[j*3+2] * INV_SQRT2 - piz;
            float njx = nuv[j*9+0], njy = nuv[j*9+1], njz = nuv[j*9+2];
            float dot = ni[0]*njx + ni[1]*njy + ni[2]*njz;
            float t = 2.f - dot;
            float d2 = (px*px + py*py + pz*pz) * (t * t);
            float w = __expf(-d2);
            float X0 = ni[0]*px + ni[1]*py + ni[2]*pz;
            float X1 = ni[3]*px + ni[4]*py + ni[5]*pz;
            float X2 = ni[6]*px + ni[7]*py + ni[8]*pz;
#pragma unroll
            for (int cc = 0; cc < 8; ++cc) {
                float hv = fmaf(X0, a1v[cc][0],
                           fmaf(X1, a1v[cc][1],
                           fmaf(X2, a1v[cc][2], c1v[cc])));
                hv = fmaxf(hv, 0.f);
                pair_s[wid][lane][cc] = w * hv;
            }
            pair_s[wid][lane][8] = w;
        }
        __syncthreads();
        // phase 2: 64 j's, each lane one channel
#pragma unroll 4
        for (int jj = 0; jj < 64; ++jj) {
            const float* p = &pair_s[wid][jj][0];
            float4 p0 = *(const float4*)p;
            float4 p1 = *(const float4*)(p + 4);
            float p8 = p[8];
            float z = p8 * c2r;
            z = fmaf(p0.x, a2r[0], z);
            z = fmaf(p0.y, a2r[1], z);
            z = fmaf(p0.z, a2r[2], z);
            z = fmaf(p0.w, a2r[3], z);
            z = fmaf(p1.x, a2r[4], z);
            z = fmaf(p1.y, a2r[5], z);
            z = fmaf(p1.z, a2r[6], z);
            z = fmaf(p1.w, a2r[7], z);
            z = fmaxf(z, 0.f);
            acc = fmaf(z, f_s[jj][lane], acc);
        }
    }
    out_raw[i * 64 + lane] = acc;
}

// ---------------------------------------------------------------------------
// Kernel F: apply output groupnorm affine.
// ---------------------------------------------------------------------------
__global__ __launch_bounds__(256) void apply_kernel(
    const float* __restrict__ pre, const float* __restrict__ ss,
    float* __restrict__ out)
{
    int idx = blockIdx.x * 256 + threadIdx.x;
    int c = idx & 63;
    out[idx] = pre[idx] * ss[c] + ss[64 + c];
}

// ---------------------------------------------------------------------------
extern "C" void kernel_launch(void* const* d_in, const int* in_sizes, int n_in,
                              void* d_out, int out_size, void* d_ws, size_t ws_size,
                              hipStream_t stream) {
    const float* points   = (const float*)d_in[0];
    const float* nuv      = (const float*)d_in[1];
    const float* features = (const float*)d_in[2];
    const float* W_in1    = (const float*)d_in[3];
    const float* b_in1    = (const float*)d_in[4];
    const float* W_in2    = (const float*)d_in[5];
    const float* b_in2    = (const float*)d_in[6];
    const float* gn_in_w  = (const float*)d_in[7];
    const float* gn_in_b  = (const float*)d_in[8];
    const float* A1       = (const float*)d_in[9];
    const float* c1       = (const float*)d_in[10];
    const float* A2       = (const float*)d_in[11];
    const float* c2       = (const float*)d_in[12];
    const float* W_out1   = (const float*)d_in[13];
    const float* b_out1   = (const float*)d_in[14];
    const float* W_out2   = (const float*)d_in[15];
    const float* b_out2   = (const float*)d_in[16];
    const float* gn_out_w = (const float*)d_in[17];
    const float* gn_out_b = (const float*)d_in[18];

    char* ws = (char*)d_ws;
    float* f_pre    = (float*)(ws + 0);          // 1 MB
    float* out_raw  = (float*)(ws + 1048576);    // 1 MB
    float* g_pre    = (float*)(ws + 2097152);    // 1 MB
    float* part_in  = (float*)(ws + 3145728);    // 32 KB
    float* part_out = (float*)(ws + 3178496);    // 32 KB
    float* ss_in    = (float*)(ws + 3211264);    // 512 B
    float* ss_out   = (float*)(ws + 3211776);    // 512 B

    float* outp = (float*)d_out;

    // net_in MLP + stats
    mlp_gn_kernel<<<1024, 256, 0, stream>>>(features, W_in1, b_in1, W_in2, b_in2,
                                            f_pre, part_in);
    finalize_kernel<<<1, 64, 0, stream>>>(part_in, 1024, gn_in_w, gn_in_b, ss_in);

    // pairwise interaction
    pairwise_kernel<<<1024, 256, 0, stream>>>(points, nuv, f_pre, ss_in,
                                              A1, c1, A2, c2, out_raw);

    // net_out MLP + stats
    mlp_gn_kernel<<<1024, 256, 0, stream>>>(out_raw, W_out1, b_out1, W_out2, b_out2,
                                            g_pre, part_out);
    finalize_kernel<<<1, 64, 0, stream>>>(part_out, 1024, gn_out_w, gn_out_b, ss_out);

    apply_kernel<<<1024, 256, 0, stream>>>(g_pre, ss_out, outp);
}

// Round 2
// 265.225 us; speedup vs baseline: 2.7167x; 2.7167x over previous
//
#include <hip/hip_runtime.h>
#include <hip/hip_bf16.h>
#include <math.h>

#define N_PTS 4096
#define INV_SQRT2 0.70710678118654752440f

typedef float f32x4 __attribute__((ext_vector_type(4)));
typedef short s16x4 __attribute__((ext_vector_type(4)));
typedef short s16x8 __attribute__((ext_vector_type(8)));

__device__ inline short f2bf(float x) {
    __hip_bfloat16 h = __float2bfloat16(x);
    return __builtin_bit_cast(short, h);
}

// ---- 16x16x32 bf16 (verified gfx950 builtin) ----
#define MFMA32(a, b, c) __builtin_amdgcn_mfma_f32_16x16x32_bf16((a), (b), (c), 0, 0, 0)

// ---- 16x16x16 bf16: builtin if present, else inline asm ----
#if defined(__has_builtin)
#  if __has_builtin(__builtin_amdgcn_mfma_f32_16x16x16bf16_1k)
#    define MFMA16(a, b, c) __builtin_amdgcn_mfma_f32_16x16x16bf16_1k((a), (b), (c), 0, 0, 0)
#    define HAVE_MFMA16 1
#  elif __has_builtin(__builtin_amdgcn_mfma_f32_16x16x16_bf16)
#    define MFMA16(a, b, c) __builtin_amdgcn_mfma_f32_16x16x16_bf16((a), (b), (c), 0, 0, 0)
#    define HAVE_MFMA16 1
#  endif
#endif
#ifndef HAVE_MFMA16
__device__ inline f32x4 mfma16_asm(s16x4 a, s16x4 b, f32x4 c) {
    asm volatile("s_nop 1\n\tv_mfma_f32_16x16x16_bf16 %0, %1, %2, %0"
                 : "+v"(c) : "v"(a), "v"(b));
    return c;
}
#  define MFMA16(a, b, c) mfma16_asm((a), (b), (c))
#endif

// ---------------------------------------------------------------------------
// Kernel A/D: 64->64->64 MLP with leaky relu + per-group partial stats.
// ---------------------------------------------------------------------------
__global__ __launch_bounds__(256) void mlp_gn_kernel(
    const float* __restrict__ inp,
    const float* __restrict__ W1, const float* __restrict__ b1,
    const float* __restrict__ W2, const float* __restrict__ b2,
    float* __restrict__ pre_out, float* __restrict__ partials)
{
    __shared__ float in_s[4][64];
    __shared__ float h1_s[4][64];
    __shared__ float red_s[4][8];

    const int tid = threadIdx.x;
    const int lane = tid & 63;
    const int wid = tid >> 6;
    const int n0 = blockIdx.x * 4;

    in_s[wid][lane] = inp[n0 * 64 + tid];
    __syncthreads();

    const int c = lane;
    float h = b1[c];
#pragma unroll
    for (int k4 = 0; k4 < 16; ++k4) {
        float4 wv = *(const float4*)&W1[c * 64 + k4 * 4];
        h = fmaf(in_s[wid][k4*4+0], wv.x, h);
        h = fmaf(in_s[wid][k4*4+1], wv.y, h);
        h = fmaf(in_s[wid][k4*4+2], wv.z, h);
        h = fmaf(in_s[wid][k4*4+3], wv.w, h);
    }
    h = (h >= 0.f) ? h : 0.2f * h;
    h1_s[wid][c] = h;
    __syncthreads();

    float g = b2[c];
#pragma unroll
    for (int k4 = 0; k4 < 16; ++k4) {
        float4 wv = *(const float4*)&W2[c * 64 + k4 * 4];
        g = fmaf(h1_s[wid][k4*4+0], wv.x, g);
        g = fmaf(h1_s[wid][k4*4+1], wv.y, g);
        g = fmaf(h1_s[wid][k4*4+2], wv.z, g);
        g = fmaf(h1_s[wid][k4*4+3], wv.w, g);
    }
    g = (g >= 0.f) ? g : 0.2f * g;
    pre_out[n0 * 64 + tid] = g;

    float v = g, v2 = g * g;
#pragma unroll
    for (int m = 1; m < 16; m <<= 1) {
        v  += __shfl_xor(v,  m, 64);
        v2 += __shfl_xor(v2, m, 64);
    }
    if ((lane & 15) == 0) {
        int grp = lane >> 4;
        red_s[wid][grp * 2 + 0] = v;
        red_s[wid][grp * 2 + 1] = v2;
    }
    __syncthreads();
    if (tid < 8) {
        int grp = tid >> 1, which = tid & 1;
        float s = red_s[0][grp*2+which] + red_s[1][grp*2+which]
                + red_s[2][grp*2+which] + red_s[3][grp*2+which];
        partials[blockIdx.x * 8 + grp * 2 + which] = s;
    }
}

// ---------------------------------------------------------------------------
// Kernel B/E: finalize group stats -> per-channel scale/shift. Parallelized.
// ---------------------------------------------------------------------------
__global__ __launch_bounds__(256) void finalize_kernel(
    const float* __restrict__ partials, int nblocks,
    const float* __restrict__ gw, const float* __restrict__ gb,
    float* __restrict__ ss)
{
    __shared__ float red[8][32];
    __shared__ float mean_s[4], inv_s[4];
    const int t = threadIdx.x;
    const int s = t >> 5, slot = t & 31;
    float acc = 0.f;
    for (int b = slot; b < nblocks; b += 32) acc += partials[b * 8 + s];
    red[s][slot] = acc;
    __syncthreads();
    if (t < 8) {
        float v = 0.f;
#pragma unroll
        for (int k = 0; k < 32; ++k) v += red[t][k];
        red[t][0] = v;
    }
    __syncthreads();
    if (t < 4) {
        float S = red[t * 2][0], SS = red[t * 2 + 1][0];
        const float cnt = (float)N_PTS * 16.f;
        float mean = S / cnt;
        float var = SS / cnt - mean * mean;
        mean_s[t] = mean;
        inv_s[t] = rsqrtf(var + 1e-5f);
    }
    __syncthreads();
    if (t < 64) {
        int grp = t >> 4;
        float sc = gw[t] * inv_s[grp];
        ss[t] = sc;
        ss[64 + t] = gb[t] - mean_s[grp] * sc;
    }
}

// ---------------------------------------------------------------------------
// Kernel: precompute normalized features, bf16, TRANSPOSED: fn_t[h][j].
// ---------------------------------------------------------------------------
__global__ __launch_bounds__(256) void fnt_kernel(
    const float* __restrict__ f_pre, const float* __restrict__ ss,
    short* __restrict__ fn_t)
{
    const int h = blockIdx.x >> 4;
    const int j = ((blockIdx.x & 15) << 8) + threadIdx.x;
    float v = f_pre[j * 64 + h] * ss[h] + ss[64 + h];
    fn_t[h * 4096 + j] = f2bf(v);
}

// ---------------------------------------------------------------------------
// Pairwise kernel, MFMA version.
// Block = 256 = 4 waves; wave wid owns i = blockIdx*4+wid; 64-j tiles.
//  phase1 (per lane j): geometry -> p[0..8]=(w*relu(cut_c), w), bf16 -> P_s.
//  2a: Z = relu( P(16jx32k) @ A2t(32kx16h) ) via mfma 16x16x32 (K pad 9->32)
//  2b: acc(16x16) += Z'^T @ fn  via mfma 16x16x16; diag(acc) = out row i.
//      C-layout of 2a == A-layout of 16x16x16 -> no cross-lane relayout.
// fn tile in LDS: bf16, XOR-swizzled 8B units -> conflict-free b64 B-frags.
// ---------------------------------------------------------------------------
__global__ __launch_bounds__(256, 4) void pairwise_kernel(
    const float* __restrict__ points, const float* __restrict__ nuv,
    const short* __restrict__ fn_t,
    const float* __restrict__ A1, const float* __restrict__ c1,
    const float* __restrict__ A2, const float* __restrict__ c2,
    float* __restrict__ out_raw)
{
    __shared__ short F_s[64 * 64];          // fn tile [h][j-swizzled], 8 KB
    __shared__ short P_s[4][64 * 40];       // per-wave P rows: 32 k + 8 pad, 20 KB

    const int tid = threadIdx.x;
    const int l = tid & 63;
    const int wid = tid >> 6;
    const int g = l >> 4;
    const int hl = l & 15;
    const int i = blockIdx.x * 4 + wid;

    // ---- i-side data (wave-uniform) ----
    const float pix = points[i*3+0] * INV_SQRT2;
    const float piy = points[i*3+1] * INV_SQRT2;
    const float piz = points[i*3+2] * INV_SQRT2;
    float ni[9];
#pragma unroll
    for (int k = 0; k < 9; ++k) ni[k] = nuv[i*9+k];

    float a1v[8][3], c1v[8];
#pragma unroll
    for (int cc = 0; cc < 8; ++cc) {
        a1v[cc][0] = A1[cc*3+0]; a1v[cc][1] = A1[cc*3+1]; a1v[cc][2] = A1[cc*3+2];
        c1v[cc] = c1[cc];
    }

    // ---- B operand of 2a: A2t as 16x16x32 B-frags, 4 h-tiles, in VGPRs ----
    // lane l holds B[k = 8*g+e][h = ht*16+hl];  B[c][h]=A2[h][c] (c<8), B[8]=c2, rest 0
    s16x8 Bfrag[4];
#pragma unroll
    for (int ht = 0; ht < 4; ++ht) {
        const int h = ht * 16 + hl;
        s16x8 v;
#pragma unroll
        for (int e = 0; e < 8; ++e) {
            const int k = 8 * g + e;
            float val = (k < 8) ? A2[h*8 + k] : ((k == 8) ? c2[h] : 0.f);
            v[e] = f2bf(val);
        }
        Bfrag[ht] = v;
    }

    f32x4 acc[4];
#pragma unroll
    for (int ht = 0; ht < 4; ++ht) acc[ht] = (f32x4){0.f, 0.f, 0.f, 0.f};

    for (int jc = 0; jc < 64; ++jc) {
        __syncthreads();   // previous tile fully consumed

        // ---- stage fn tile: F_s[h][unit^(h&15)] ----
        {
            const int h = tid >> 2, q4 = tid & 3, hx = h & 15, hb = h * 64;
            const short* src = fn_t + h * 4096 + jc * 64 + q4 * 16;
            s16x8 u0 = *(const s16x8*)src;
            s16x8 u1 = *(const s16x8*)(src + 8);
            *(s16x4*)&F_s[hb + (((q4*4+0) ^ hx) << 2)] = __builtin_shufflevector(u0, u0, 0,1,2,3);
            *(s16x4*)&F_s[hb + (((q4*4+1) ^ hx) << 2)] = __builtin_shufflevector(u0, u0, 4,5,6,7);
            *(s16x4*)&F_s[hb + (((q4*4+2) ^ hx) << 2)] = __builtin_shufflevector(u1, u1, 0,1,2,3);
            *(s16x4*)&F_s[hb + (((q4*4+3) ^ hx) << 2)] = __builtin_shufflevector(u1, u1, 4,5,6,7);
        }

        // ---- phase 1: per-pair scalars for j = jc*64 + l ----
        {
            const int j = jc * 64 + l;
            float px = points[j*3+0] * INV_SQRT2 - pix;
            float py = points[j*3+1] * INV_SQRT2 - piy;
            float pz = points[j*3+2] * INV_SQRT2 - piz;
            float njx = nuv[j*9+0], njy = nuv[j*9+1], njz = nuv[j*9+2];
            float dot = ni[0]*njx + ni[1]*njy + ni[2]*njz;
            float t2 = 2.f - dot;
            float d2 = (px*px + py*py + pz*pz) * (t2 * t2);
            float w = __expf(-d2);
            float X0 = ni[0]*px + ni[1]*py + ni[2]*pz;
            float X1 = ni[3]*px + ni[4]*py + ni[5]*pz;
            float X2 = ni[6]*px + ni[7]*py + ni[8]*pz;

            s16x8 pk0;
#pragma unroll
            for (int cc = 0; cc < 8; ++cc) {
                float hv = fmaf(X0, a1v[cc][0],
                           fmaf(X1, a1v[cc][1],
                           fmaf(X2, a1v[cc][2], c1v[cc])));
                hv = fmaxf(hv, 0.f);
                pk0[cc] = f2bf(w * hv);
            }
            s16x8 pk1 = (s16x8){0,0,0,0,0,0,0,0};
            pk1[0] = f2bf(w);
            s16x8 zz = (s16x8){0,0,0,0,0,0,0,0};
            short* row = &P_s[wid][l * 40];
            *(s16x8*)(row +  0) = pk0;
            *(s16x8*)(row +  8) = pk1;
            *(s16x8*)(row + 16) = zz;
            *(s16x8*)(row + 24) = zz;
        }
        __syncthreads();   // F_s + P_s published

        // ---- 2a + 2b ----
#pragma unroll
        for (int jsub = 0; jsub < 4; ++jsub) {
            const s16x8 Af = *(const s16x8*)&P_s[wid][(jsub*16 + hl) * 40 + g * 8];
#pragma unroll
            for (int ht = 0; ht < 4; ++ht) {
                f32x4 z = MFMA32(Af, Bfrag[ht], ((f32x4){0.f,0.f,0.f,0.f}));
                s16x4 az;
                az[0] = f2bf(fmaxf(z[0], 0.f));
                az[1] = f2bf(fmaxf(z[1], 0.f));
                az[2] = f2bf(fmaxf(z[2], 0.f));
                az[3] = f2bf(fmaxf(z[3], 0.f));
                const s16x4 bf = *(const s16x4*)&F_s[(ht*16 + hl) * 64 + (((jsub*4 + g) ^ hl) << 2)];
                acc[ht] = MFMA16(az, bf, acc[ht]);
            }
        }
    }

    // MFMA->VALU read guard (needed if asm fallback was used; harmless otherwise)
    asm volatile("s_nop 7\n\ts_nop 7" ::: );

    // ---- epilogue: diag extraction. lane with l>>4 == (l&15)>>2 holds diag(m=hl) ----
    if (g == (hl >> 2)) {
        const int r = hl & 3;
#pragma unroll
        for (int ht = 0; ht < 4; ++ht) {
            float v = (r == 0) ? acc[ht][0] : (r == 1) ? acc[ht][1]
                    : (r == 2) ? acc[ht][2] : acc[ht][3];
            out_raw[i * 64 + ht * 16 + hl] = v;
        }
    }
}

// ---------------------------------------------------------------------------
// Kernel F: apply output groupnorm affine.
// ---------------------------------------------------------------------------
__global__ __launch_bounds__(256) void apply_kernel(
    const float* __restrict__ pre, const float* __restrict__ ss,
    float* __restrict__ out)
{
    int idx = blockIdx.x * 256 + threadIdx.x;
    int c = idx & 63;
    out[idx] = pre[idx] * ss[c] + ss[64 + c];
}

// ---------------------------------------------------------------------------
extern "C" void kernel_launch(void* const* d_in, const int* in_sizes, int n_in,
                              void* d_out, int out_size, void* d_ws, size_t ws_size,
                              hipStream_t stream) {
    const float* points   = (const float*)d_in[0];
    const float* nuv      = (const float*)d_in[1];
    const float* features = (const float*)d_in[2];
    const float* W_in1    = (const float*)d_in[3];
    const float* b_in1    = (const float*)d_in[4];
    const float* W_in2    = (const float*)d_in[5];
    const float* b_in2    = (const float*)d_in[6];
    const float* gn_in_w  = (const float*)d_in[7];
    const float* gn_in_b  = (const float*)d_in[8];
    const float* A1       = (const float*)d_in[9];
    const float* c1       = (const float*)d_in[10];
    const float* A2       = (const float*)d_in[11];
    const float* c2       = (const float*)d_in[12];
    const float* W_out1   = (const float*)d_in[13];
    const float* b_out1   = (const float*)d_in[14];
    const float* W_out2   = (const float*)d_in[15];
    const float* b_out2   = (const float*)d_in[16];
    const float* gn_out_w = (const float*)d_in[17];
    const float* gn_out_b = (const float*)d_in[18];

    char* ws = (char*)d_ws;
    float* f_pre    = (float*)(ws + 0);            // 1 MB   (aliased by g_pre later)
    float* g_pre    = (float*)(ws + 0);            // 1 MB   (liveness-disjoint with f_pre)
    float* out_raw  = (float*)(ws + 1048576);      // 1 MB
    short* fn_t     = (short*)(ws + 2097152);      // 512 KB (bf16, transposed [64][4096])
    float* part_in  = (float*)(ws + 2621440);      // 32 KB
    float* part_out = (float*)(ws + 2654208);      // 32 KB
    float* ss_in    = (float*)(ws + 2686976);      // 512 B
    float* ss_out   = (float*)(ws + 2687488);      // 512 B

    float* outp = (float*)d_out;

    // net_in MLP + stats
    mlp_gn_kernel<<<1024, 256, 0, stream>>>(features, W_in1, b_in1, W_in2, b_in2,
                                            f_pre, part_in);
    finalize_kernel<<<1, 256, 0, stream>>>(part_in, 1024, gn_in_w, gn_in_b, ss_in);

    // normalized features, bf16, transposed
    fnt_kernel<<<1024, 256, 0, stream>>>(f_pre, ss_in, fn_t);

    // pairwise interaction (MFMA)
    pairwise_kernel<<<1024, 256, 0, stream>>>(points, nuv, fn_t,
                                              A1, c1, A2, c2, out_raw);

    // net_out MLP + stats
    mlp_gn_kernel<<<1024, 256, 0, stream>>>(out_raw, W_out1, b_out1, W_out2, b_out2,
                                            g_pre, part_out);
    finalize_kernel<<<1, 256, 0, stream>>>(part_out, 1024, gn_out_w, gn_out_b, ss_out);

    apply_kernel<<<1024, 256, 0, stream>>>(g_pre, ss_out, outp);
}